// Round 2
// baseline (147.398 us; speedup 1.0000x reference)
//
#include <hip/hip_runtime.h>

// OSTL spiking-LIF forward:  Y = X @ K  (512x1024x1024 fp32 GEMM), then
// per-column scan: u = sig*u + Y[t], s = u>1, u -= s.
// Spikes [512,1024] then u_final [1024] packed into d_out.
// Y is staged in the spikes region of d_out and overwritten in place.

#define T_STEPS 512
#define IN_SZ   1024
#define OUT_SZ  1024

#define BM 32
#define BN 64
#define BK 32

__global__ __launch_bounds__(256) void ostl_gemm_kernel(const float* __restrict__ X,
                                                        const float* __restrict__ W,
                                                        float* __restrict__ Y) {
    __shared__ float As[BK][BM + 4];   // A tile stored transposed [k][m], padded
    __shared__ float Bs[BK][BN];       // B tile [k][n]

    const int tid = threadIdx.x;
    const int m0 = blockIdx.y * BM;
    const int n0 = blockIdx.x * BN;
    const int tx = tid & 15;    // col group: cols tx*4 .. tx*4+3
    const int ty = tid >> 4;    // row group: rows ty*2, ty*2+1

    float acc[2][4] = {};

    for (int k0 = 0; k0 < IN_SZ; k0 += BK) {
        // Load A tile 32x32 (one float4 per thread), store transposed.
        {
            const int r  = tid >> 3;        // 0..31
            const int kq = (tid & 7) << 2;  // 0,4,...,28
            const float4 a = *reinterpret_cast<const float4*>(&X[(size_t)(m0 + r) * IN_SZ + k0 + kq]);
            As[kq + 0][r] = a.x;
            As[kq + 1][r] = a.y;
            As[kq + 2][r] = a.z;
            As[kq + 3][r] = a.w;
        }
        // Load B tile 32x64 (two float4 per thread).
        #pragma unroll
        for (int l = 0; l < 2; ++l) {
            const int idx = l * 1024 + tid * 4;
            const int kr = idx >> 6;     // 0..31
            const int c  = idx & 63;
            *reinterpret_cast<float4*>(&Bs[kr][c]) =
                *reinterpret_cast<const float4*>(&W[(size_t)(k0 + kr) * OUT_SZ + n0 + c]);
        }
        __syncthreads();

        // Per-BK-tile partial accumulator (pairwise-style summation keeps
        // fp32 error ~4e-7 so no spike flips vs the reference).
        float part[2][4] = {};
        #pragma unroll
        for (int k = 0; k < BK; ++k) {
            const float2 a = *reinterpret_cast<const float2*>(&As[k][ty * 2]);
            const float4 b = *reinterpret_cast<const float4*>(&Bs[k][tx * 4]);
            part[0][0] += a.x * b.x; part[0][1] += a.x * b.y;
            part[0][2] += a.x * b.z; part[0][3] += a.x * b.w;
            part[1][0] += a.y * b.x; part[1][1] += a.y * b.y;
            part[1][2] += a.y * b.z; part[1][3] += a.y * b.w;
        }
        #pragma unroll
        for (int i = 0; i < 2; ++i)
            #pragma unroll
            for (int j = 0; j < 4; ++j)
                acc[i][j] += part[i][j];

        __syncthreads();
    }

    #pragma unroll
    for (int i = 0; i < 2; ++i) {
        const float4 v = make_float4(acc[i][0], acc[i][1], acc[i][2], acc[i][3]);
        *reinterpret_cast<float4*>(&Y[(size_t)(m0 + ty * 2 + i) * OUT_SZ + n0 + tx * 4]) = v;
    }
}

__global__ __launch_bounds__(64) void ostl_scan_kernel(const float* __restrict__ u0,
                                                       float* __restrict__ Yspk,
                                                       float* __restrict__ u_final) {
    const int j = blockIdx.x * blockDim.x + threadIdx.x;
    if (j >= OUT_SZ) return;

    // sigmoid(2.0) rounded to fp32 (reference computes it in fp32), then
    // run the recurrence in double so our u tracks the true value to ~1e-15
    // per step; spike decisions then match both fp32-jax and np references
    // (their mutual agreement implies all margins >> 1e-6).
    const float  sig_f   = (float)0.8807970779778823;
    const double sig_tau = (double)sig_f;

    double u = (double)u0[j];
    float* p = Yspk + j;

    for (int t = 0; t < T_STEPS; ++t) {
        const float y = p[(size_t)t * OUT_SZ];
        u = sig_tau * u + (double)y;
        const float s = (u > 1.0) ? 1.0f : 0.0f;
        p[(size_t)t * OUT_SZ] = s;   // overwrite Y with the spike in place
        u -= (double)s;
    }
    u_final[j] = (float)u;
}

extern "C" void kernel_launch(void* const* d_in, const int* in_sizes, int n_in,
                              void* d_out, int out_size, void* d_ws, size_t ws_size,
                              hipStream_t stream) {
    const float* x_seq  = (const float*)d_in[0];   // [512,1024]
    const float* kernel = (const float*)d_in[1];   // [1024,1024]
    const float* u0     = (const float*)d_in[2];   // [1024]
    // d_in[3] = E0: unused in the primal path.

    float* out      = (float*)d_out;
    float* spikes   = out;                         // [512,1024] (staging for Y, then spikes)
    float* u_final  = out + (size_t)T_STEPS * OUT_SZ;

    dim3 gemm_grid(OUT_SZ / BN, T_STEPS / BM);     // (16, 16)
    ostl_gemm_kernel<<<gemm_grid, dim3(256), 0, stream>>>(x_seq, kernel, spikes);

    ostl_scan_kernel<<<dim3(OUT_SZ / 64), dim3(64), 0, stream>>>(u0, spikes, u_final);
}

// Round 5
// 116.688 us; speedup vs baseline: 1.2632x; 1.2632x over previous
//
#include <hip/hip_runtime.h>

// OSTL spiking-LIF forward:  Y = X @ K  (512x1024x1024 fp32 GEMM), then
// per-column scan: u = sig*u + Y[t], s = u>1, u -= s.
// Spikes [512,1024] then u_final [1024] packed into d_out.
// Y is staged in the spikes region of d_out and overwritten in place.
//
// R3: (1) GEMM double-buffered LDS + global->reg prefetch (1 barrier/iter) —
//     hides ~900cy global latency that was fully exposed with 1 wave/SIMD.
//     (2) Scan: explicit 16-step register double-buffer prefetch — hides the
//     ~225cy per-load latency chain that made R2's scan 48us.
// Numerics are BITWISE IDENTICAL to the passing R2 kernel (same BK-chunk
// partial-sum order, same inner FMA order, same double-precision scan).

#define T_STEPS 512
#define IN_SZ   1024
#define OUT_SZ  1024

#define BM 32
#define BN 64
#define BK 32

__global__ __launch_bounds__(256) void ostl_gemm_kernel(const float* __restrict__ X,
                                                        const float* __restrict__ W,
                                                        float* __restrict__ Y) {
    __shared__ float As[2][BK][BM + 4];   // A stored transposed [k][m], padded
    __shared__ float Bs[2][BK][BN];       // B tile [k][n]

    const int tid = threadIdx.x;
    const int m0 = blockIdx.y * BM;
    const int n0 = blockIdx.x * BN;
    const int tx = tid & 15;        // col group: cols tx*4 .. tx*4+3
    const int ty = tid >> 4;        // row group: rows ty*2, ty*2+1

    // Staging-load mappings (same as R2).
    const int ar  = tid >> 3;         // A row 0..31
    const int akq = (tid & 7) << 2;   // A k-quad 0,4,...,28
    const int bkr = tid >> 4;         // B k-row 0..15 (plus +16 for 2nd half)
    const int bc  = (tid * 4) & 63;   // B col

    const float* Arow = &X[(size_t)(m0 + ar) * IN_SZ + akq];
    const float* Bp0  = &W[(size_t)bkr        * OUT_SZ + n0 + bc];
    const float* Bp1  = &W[(size_t)(bkr + 16) * OUT_SZ + n0 + bc];

    float4 aReg, bReg0, bReg1;

    // ---- prologue: tile 0 -> LDS buf0; tile 1 -> regs ----
    aReg  = *reinterpret_cast<const float4*>(Arow);
    bReg0 = *reinterpret_cast<const float4*>(Bp0);
    bReg1 = *reinterpret_cast<const float4*>(Bp1);
    As[0][akq + 0][ar] = aReg.x;
    As[0][akq + 1][ar] = aReg.y;
    As[0][akq + 2][ar] = aReg.z;
    As[0][akq + 3][ar] = aReg.w;
    *reinterpret_cast<float4*>(&Bs[0][bkr][bc])      = bReg0;
    *reinterpret_cast<float4*>(&Bs[0][bkr + 16][bc]) = bReg1;
    aReg  = *reinterpret_cast<const float4*>(Arow + BK);
    bReg0 = *reinterpret_cast<const float4*>(Bp0 + (size_t)BK * OUT_SZ);
    bReg1 = *reinterpret_cast<const float4*>(Bp1 + (size_t)BK * OUT_SZ);
    __syncthreads();

    float acc[2][4] = {};

    #pragma unroll 1
    for (int it = 0; it < IN_SZ / BK; ++it) {
        const int cur = it & 1;

        // Per-BK-tile partial accumulator — EXACT same FMA order as R2
        // (pairwise-style summation; keeps fp32 error ~4e-7, no spike flips).
        float part[2][4] = {};
        #pragma unroll
        for (int k = 0; k < BK; ++k) {
            const float2 a = *reinterpret_cast<const float2*>(&As[cur][k][ty * 2]);
            const float4 b = *reinterpret_cast<const float4*>(&Bs[cur][k][tx * 4]);
            part[0][0] += a.x * b.x; part[0][1] += a.x * b.y;
            part[0][2] += a.x * b.z; part[0][3] += a.x * b.w;
            part[1][0] += a.y * b.x; part[1][1] += a.y * b.y;
            part[1][2] += a.y * b.z; part[1][3] += a.y * b.w;
        }
        #pragma unroll
        for (int i = 0; i < 2; ++i)
            #pragma unroll
            for (int j = 0; j < 4; ++j)
                acc[i][j] += part[i][j];

        if (it < IN_SZ / BK - 1) {
            const int nxt = cur ^ 1;
            // regs hold tile it+1: write into the other LDS buffer
            As[nxt][akq + 0][ar] = aReg.x;
            As[nxt][akq + 1][ar] = aReg.y;
            As[nxt][akq + 2][ar] = aReg.z;
            As[nxt][akq + 3][ar] = aReg.w;
            *reinterpret_cast<float4*>(&Bs[nxt][bkr][bc])      = bReg0;
            *reinterpret_cast<float4*>(&Bs[nxt][bkr + 16][bc]) = bReg1;
            if (it < IN_SZ / BK - 2) {
                const int k0 = (it + 2) * BK;
                aReg  = *reinterpret_cast<const float4*>(Arow + k0);
                bReg0 = *reinterpret_cast<const float4*>(Bp0 + (size_t)k0 * OUT_SZ);
                bReg1 = *reinterpret_cast<const float4*>(Bp1 + (size_t)k0 * OUT_SZ);
            }
            __syncthreads();
        }
    }

    #pragma unroll
    for (int i = 0; i < 2; ++i) {
        const float4 v = make_float4(acc[i][0], acc[i][1], acc[i][2], acc[i][3]);
        *reinterpret_cast<float4*>(&Y[(size_t)(m0 + ty * 2 + i) * OUT_SZ + n0 + tx * 4]) = v;
    }
}

#define TB 16   // scan timestep block (register-buffered)

__global__ __launch_bounds__(64) void ostl_scan_kernel(const float* __restrict__ u0,
                                                       float* __restrict__ Yspk,
                                                       float* __restrict__ u_final) {
    const int j = blockIdx.x * blockDim.x + threadIdx.x;
    if (j >= OUT_SZ) return;

    // Same constants/precision as R2 (bitwise-identical trajectory).
    const float  sig_f   = (float)0.8807970779778823;
    const double sig_tau = (double)sig_f;

    double u = (double)u0[j];
    float* p = Yspk + j;

    float bA[TB], bB[TB];

    // preload block 0
    #pragma unroll
    for (int i = 0; i < TB; ++i) bA[i] = p[(size_t)i * OUT_SZ];

    #pragma unroll 1
    for (int blk = 0; blk < T_STEPS / TB; blk += 2) {
        // issue loads for block blk+1 (independent; hide under compute of blk)
        #pragma unroll
        for (int i = 0; i < TB; ++i)
            bB[i] = p[(size_t)((blk + 1) * TB + i) * OUT_SZ];

        // compute block blk from bA
        #pragma unroll
        for (int i = 0; i < TB; ++i) {
            u = fma(sig_tau, u, (double)bA[i]);
            const float s = (u > 1.0) ? 1.0f : 0.0f;
            p[(size_t)(blk * TB + i) * OUT_SZ] = s;
            u -= (double)s;
        }

        // issue loads for block blk+2
        if (blk + 2 < T_STEPS / TB) {
            #pragma unroll
            for (int i = 0; i < TB; ++i)
                bA[i] = p[(size_t)((blk + 2) * TB + i) * OUT_SZ];
        }

        // compute block blk+1 from bB
        #pragma unroll
        for (int i = 0; i < TB; ++i) {
            u = fma(sig_tau, u, (double)bB[i]);
            const float s = (u > 1.0) ? 1.0f : 0.0f;
            p[(size_t)((blk + 1) * TB + i) * OUT_SZ] = s;
            u -= (double)s;
        }
    }
    u_final[j] = (float)u;
}

extern "C" void kernel_launch(void* const* d_in, const int* in_sizes, int n_in,
                              void* d_out, int out_size, void* d_ws, size_t ws_size,
                              hipStream_t stream) {
    const float* x_seq  = (const float*)d_in[0];   // [512,1024]
    const float* kernel = (const float*)d_in[1];   // [1024,1024]
    const float* u0     = (const float*)d_in[2];   // [1024]
    // d_in[3] = E0: unused in the primal path.

    float* out      = (float*)d_out;
    float* spikes   = out;                         // [512,1024] (staging for Y, then spikes)
    float* u_final  = out + (size_t)T_STEPS * OUT_SZ;

    dim3 gemm_grid(OUT_SZ / BN, T_STEPS / BM);     // (16, 16)
    ostl_gemm_kernel<<<gemm_grid, dim3(256), 0, stream>>>(x_seq, kernel, spikes);

    ostl_scan_kernel<<<dim3(OUT_SZ / 64), dim3(64), 0, stream>>>(u0, spikes, u_final);
}

// Round 7
// 112.401 us; speedup vs baseline: 1.3114x; 1.0381x over previous
//
#include <hip/hip_runtime.h>
#include <stdint.h>

// OSTL spiking-LIF forward.
// R6: GEMM rebuilt as split-K=8, 128x128 tile, 8x8 per-thread register tile.
//   LDS traffic drops 3B/MAC -> 1B/MAC (the R5 GEMM was LDS-throughput-bound
//   at ~31us by the 52TB/s ds_read ceiling). B staged via global_load_lds
//   (width 16, linear dest); A reg-staged transposed. Partials -> d_ws,
//   deterministic pairwise tree-reduce -> Y, then the proven f64 scan
//   (now alias-free: reads ws, writes d_out).

#define T_STEPS 512
#define IN_SZ   1024
#define OUT_SZ  1024

#define BM 128
#define BN 128
#define BK 32
#define KSPLIT 8
#define KCHUNK (IN_SZ / KSPLIT)    // 128
#define NITER  (KCHUNK / BK)       // 4

typedef __attribute__((address_space(1))) const void gvoid;
typedef __attribute__((address_space(3))) void lvoid;

__global__ __launch_bounds__(256) void ostl_gemm_splitk(const float* __restrict__ X,
                                                        const float* __restrict__ W,
                                                        float* __restrict__ P) {
    __shared__ float As[2][BK][BM];     // A stored transposed [k][m]; reads are
                                        // 4-addr broadcast (conflict-free), writes 2-way (free)
    __shared__ float Bs[2][BK * BN];    // linear [k][n]; written by global_load_lds

    const int tid = threadIdx.x;
    const int tx = tid & 15;            // output cols tx*4..+3 and tx*4+64..+67
    const int ty = tid >> 4;            // output rows ty*8..+7
    const int n0 = blockIdx.x * BN;
    const int m0 = blockIdx.y * BM;
    const int kc = blockIdx.z;
    const int kb = kc * KCHUNK;

    const int am = tid >> 1;            // A row this thread stages (0..127)
    const int ak = (tid & 1) * 16;      // A k-offset within tile (0 or 16)
    const int wv = tid >> 6;            // wave id 0..3
    const int ln = tid & 63;            // lane id

    const float* Arow = X + (size_t)(m0 + am) * IN_SZ + kb + ak;

    float4 areg[4];

    // ---- prologue: stage tile 0 into buffer 0 ----
    #pragma unroll
    for (int q = 0; q < 4; ++q)
        areg[q] = *reinterpret_cast<const float4*>(Arow + q * 4);
    #pragma unroll
    for (int j = 0; j < 4; ++j) {
        const int i = wv * 4 + j;       // 16 instrs/block, each fills 2 k-rows (1KB)
        const float* src = W + (size_t)(kb + 2 * i + (ln >> 5)) * OUT_SZ + n0 + (ln & 31) * 4;
        __builtin_amdgcn_global_load_lds((gvoid*)src, (lvoid*)&Bs[0][i * 256], 16, 0, 0);
    }
    {
        float t[16];
        #pragma unroll
        for (int q = 0; q < 4; ++q) *reinterpret_cast<float4*>(&t[q * 4]) = areg[q];
        #pragma unroll
        for (int c = 0; c < 16; ++c) As[0][ak + c][am] = t[c];
    }
    __syncthreads();

    float acc[8][8];
    #pragma unroll
    for (int r = 0; r < 8; ++r)
        #pragma unroll
        for (int c = 0; c < 8; ++c) acc[r][c] = 0.f;

    #pragma unroll 1
    for (int it = 0; it < NITER; ++it) {
        const int cur = it & 1;
        const int nxt = cur ^ 1;

        // issue next tile's loads first; the 4096-cyc compute hides them
        if (it < NITER - 1) {
            const int kbase = kb + (it + 1) * BK;
            #pragma unroll
            for (int j = 0; j < 4; ++j) {
                const int i = wv * 4 + j;
                const float* src = W + (size_t)(kbase + 2 * i + (ln >> 5)) * OUT_SZ + n0 + (ln & 31) * 4;
                __builtin_amdgcn_global_load_lds((gvoid*)src, (lvoid*)&Bs[nxt][i * 256], 16, 0, 0);
            }
            #pragma unroll
            for (int q = 0; q < 4; ++q)
                areg[q] = *reinterpret_cast<const float4*>(Arow + (it + 1) * BK + q * 4);
        }

        // 64 MACs per 64 LDS bytes per k-step (1 B/MAC)
        #pragma unroll 8
        for (int k = 0; k < BK; ++k) {
            const float4 a0 = *reinterpret_cast<const float4*>(&As[cur][k][ty * 8]);
            const float4 a1 = *reinterpret_cast<const float4*>(&As[cur][k][ty * 8 + 4]);
            const float4 b0 = *reinterpret_cast<const float4*>(&Bs[cur][k * BN + tx * 4]);
            const float4 b1 = *reinterpret_cast<const float4*>(&Bs[cur][k * BN + tx * 4 + 64]);
            const float av[8] = {a0.x, a0.y, a0.z, a0.w, a1.x, a1.y, a1.z, a1.w};
            const float bv[8] = {b0.x, b0.y, b0.z, b0.w, b1.x, b1.y, b1.z, b1.w};
            #pragma unroll
            for (int r = 0; r < 8; ++r)
                #pragma unroll
                for (int c = 0; c < 8; ++c)
                    acc[r][c] = fmaf(av[r], bv[c], acc[r][c]);
        }

        if (it < NITER - 1) {
            float t[16];
            #pragma unroll
            for (int q = 0; q < 4; ++q) *reinterpret_cast<float4*>(&t[q * 4]) = areg[q];
            #pragma unroll
            for (int c = 0; c < 16; ++c) As[nxt][ak + c][am] = t[c];
            __syncthreads();
        }
    }

    // partial for k-chunk kc
    float* Pb = P + (size_t)kc * T_STEPS * OUT_SZ + (size_t)(m0 + ty * 8) * OUT_SZ + n0;
    #pragma unroll
    for (int r = 0; r < 8; ++r) {
        *reinterpret_cast<float4*>(&Pb[(size_t)r * OUT_SZ + tx * 4]) =
            make_float4(acc[r][0], acc[r][1], acc[r][2], acc[r][3]);
        *reinterpret_cast<float4*>(&Pb[(size_t)r * OUT_SZ + tx * 4 + 64]) =
            make_float4(acc[r][4], acc[r][5], acc[r][6], acc[r][7]);
    }
}

__device__ inline float4 f4add(float4 a, float4 b) {
    return make_float4(a.x + b.x, a.y + b.y, a.z + b.z, a.w + b.w);
}

// deterministic pairwise tree over the 8 k-chunk partials
__global__ __launch_bounds__(256) void ostl_reduce8(const float* __restrict__ P,
                                                    float* __restrict__ Y) {
    const size_t idx = ((size_t)blockIdx.x * 256 + threadIdx.x) * 4;
    float4 s[8];
    #pragma unroll
    for (int c = 0; c < 8; ++c)
        s[c] = *reinterpret_cast<const float4*>(P + (size_t)c * T_STEPS * OUT_SZ + idx);
    const float4 t0 = f4add(s[0], s[1]);
    const float4 t1 = f4add(s[2], s[3]);
    const float4 t2 = f4add(s[4], s[5]);
    const float4 t3 = f4add(s[6], s[7]);
    *reinterpret_cast<float4*>(Y + idx) = f4add(f4add(t0, t1), f4add(t2, t3));
}

#define TB 16   // scan timestep block (register double-buffered)

__global__ __launch_bounds__(64) void ostl_scan_kernel(const float* __restrict__ u0,
                                                       const float* __restrict__ Yin,
                                                       float* __restrict__ Sout,
                                                       float* __restrict__ u_final) {
    const int j = blockIdx.x * blockDim.x + threadIdx.x;
    if (j >= OUT_SZ) return;

    // Same constants/precision as the passing R2/R5 scan.
    const float  sig_f   = (float)0.8807970779778823;
    const double sig_tau = (double)sig_f;

    double u = (double)u0[j];
    const float* pin = Yin + j;
    float* pout = Sout + j;

    float bA[TB], bB[TB];

    #pragma unroll
    for (int i = 0; i < TB; ++i) bA[i] = pin[(size_t)i * OUT_SZ];

    #pragma unroll 1
    for (int blk = 0; blk < T_STEPS / TB; blk += 2) {
        #pragma unroll
        for (int i = 0; i < TB; ++i)
            bB[i] = pin[(size_t)((blk + 1) * TB + i) * OUT_SZ];

        #pragma unroll
        for (int i = 0; i < TB; ++i) {
            u = fma(sig_tau, u, (double)bA[i]);
            const float s = (u > 1.0) ? 1.0f : 0.0f;
            pout[(size_t)(blk * TB + i) * OUT_SZ] = s;
            u -= (double)s;
        }

        if (blk + 2 < T_STEPS / TB) {
            #pragma unroll
            for (int i = 0; i < TB; ++i)
                bA[i] = pin[(size_t)((blk + 2) * TB + i) * OUT_SZ];
        }

        #pragma unroll
        for (int i = 0; i < TB; ++i) {
            u = fma(sig_tau, u, (double)bB[i]);
            const float s = (u > 1.0) ? 1.0f : 0.0f;
            pout[(size_t)((blk + 1) * TB + i) * OUT_SZ] = s;
            u -= (double)s;
        }
    }
    u_final[j] = (float)u;
}

extern "C" void kernel_launch(void* const* d_in, const int* in_sizes, int n_in,
                              void* d_out, int out_size, void* d_ws, size_t ws_size,
                              hipStream_t stream) {
    const float* x_seq  = (const float*)d_in[0];   // [512,1024]
    const float* kernel = (const float*)d_in[1];   // [1024,1024]
    const float* u0     = (const float*)d_in[2];   // [1024]
    // d_in[3] = E0: unused in the primal path.

    float* out      = (float*)d_out;
    float* spikes   = out;                               // [512,1024]
    float* u_final  = out + (size_t)T_STEPS * OUT_SZ;    // [1024]

    float* partials = (float*)d_ws;                      // 8 x [512,1024] = 16 MB
    float* yb       = partials + (size_t)KSPLIT * T_STEPS * OUT_SZ;  // [512,1024] = 2 MB

    dim3 ggrid(OUT_SZ / BN, T_STEPS / BM, KSPLIT);       // (8, 4, 8) = 256 blocks
    ostl_gemm_splitk<<<ggrid, dim3(256), 0, stream>>>(x_seq, kernel, partials);

    ostl_reduce8<<<dim3((T_STEPS * OUT_SZ / 4) / 256), dim3(256), 0, stream>>>(partials, yb);

    ostl_scan_kernel<<<dim3(OUT_SZ / 64), dim3(64), 0, stream>>>(u0, yb, spikes, u_final);
}